// Round 12
// baseline (1387.394 us; speedup 1.0000x reference)
//
#include <hip/hip_runtime.h>
#include <hip/hip_bf16.h>
#include <math.h>

#define BSZ 8
#define SEQL 1024
#define DM 512
#define DI 1024
#define DST 16
#define DTR 32
#define NLAYERS 4
#define ALPHA_C 0.2f
#define LNEPS 1e-5f
#define CH 64          // scan LDS chunk length (t-steps)
#define KS64 8         // split-K for the skinny N=64 MFMA GEMM
#define YSTR 18        // yb row stride (dwords)
#define SROW 68        // scan staging row stride (dwords): 272B = 17*16B, 16B-aligned rows

typedef __attribute__((ext_vector_type(8))) short short8;
typedef __attribute__((ext_vector_type(4))) float f32x4;

__device__ __forceinline__ void gll16(const void* g, void* l) {
    __builtin_amdgcn_global_load_lds(
        (const __attribute__((address_space(1))) unsigned int*)g,
        (__attribute__((address_space(3))) unsigned int*)l, 16, 0, 0);
}

__device__ __forceinline__ float sum16(float x) {
    x += __int_as_float(__builtin_amdgcn_update_dpp(0, __float_as_int(x), 0x121, 0xf, 0xf, true));
    x += __int_as_float(__builtin_amdgcn_update_dpp(0, __float_as_int(x), 0x122, 0xf, 0xf, true));
    x += __int_as_float(__builtin_amdgcn_update_dpp(0, __float_as_int(x), 0x124, 0xf, 0xf, true));
    x += __int_as_float(__builtin_amdgcn_update_dpp(0, __float_as_int(x), 0x128, 0xf, 0xf, true));
    return x;
}

__device__ __forceinline__ float bf2f(unsigned short v) {
    return __uint_as_float(((unsigned)v) << 16);
}

// ---------------- input embedding ----------------
__global__ __launch_bounds__(256) void embed_kernel(const float* __restrict__ x,
                                                    const float* __restrict__ Wi,
                                                    const float* __restrict__ bi,
                                                    float* __restrict__ t) {
    int idx = blockIdx.x * 256 + threadIdx.x;
    if (idx >= BSZ * SEQL * DM) return;
    int d  = idx & (DM - 1);
    int bl = idx >> 9;
    int l  = bl & (SEQL - 1);
    int b  = bl >> 10;
    const float* xb = x + (size_t)b * 3 * SEQL;
    float acc = bi[d];
    acc += xb[0 * SEQL + l] * Wi[0 * DM + d];
    acc += xb[1 * SEQL + l] * Wi[1 * DM + d];
    acc += xb[2 * SEQL + l] * Wi[2 * DM + d];
    t[idx] = acc;
}

// ---------------- layernorm over DM=512, writes bf16 ----------------
__global__ __launch_bounds__(256) void ln_kernel(const float* __restrict__ t,
                                                 const float* __restrict__ w,
                                                 const float* __restrict__ b,
                                                 __hip_bfloat16* __restrict__ xn) {
    int row = blockIdx.x;
    int tid = threadIdx.x;
    const float* r = t + (size_t)row * DM;
    float v0 = r[tid], v1 = r[tid + 256];
    __shared__ float sh[256], sh2[256];
    sh[tid]  = v0 + v1;
    sh2[tid] = v0 * v0 + v1 * v1;
    __syncthreads();
    for (int off = 128; off > 0; off >>= 1) {
        if (tid < off) { sh[tid] += sh[tid + off]; sh2[tid] += sh2[tid + off]; }
        __syncthreads();
    }
    float mu  = sh[0]  * (1.f / DM);
    float var = sh2[0] * (1.f / DM) - mu * mu;
    float rs  = rsqrtf(var + LNEPS);
    xn[(size_t)row * DM + tid]       = __float2bfloat16((v0 - mu) * rs * w[tid]       + b[tid]);
    xn[(size_t)row * DM + tid + 256] = __float2bfloat16((v1 - mu) * rs * w[tid + 256] + b[tid + 256]);
}

// ---------------- transpose + fp32->bf16: W[K][N] -> Wt[N][K] ----------------
__global__ __launch_bounds__(256) void transpose_bf_kernel(const float* __restrict__ W,
                                                           __hip_bfloat16* __restrict__ Wt,
                                                           int K, int N, size_t lstride) {
    const float* Wl = W + (size_t)blockIdx.z * lstride;
    __hip_bfloat16* Wtl = Wt + (size_t)blockIdx.z * lstride;
    __shared__ float tile[32][33];
    int kk = blockIdx.x * 32, nn = blockIdx.y * 32;
    int tx = threadIdx.x & 31, ty = threadIdx.x >> 5;
#pragma unroll
    for (int i = 0; i < 32; i += 8)
        tile[ty + i][tx] = Wl[(size_t)(kk + ty + i) * N + nn + tx];
    __syncthreads();
#pragma unroll
    for (int i = 0; i < 32; i += 8)
        Wtl[(size_t)(nn + ty + i) * K + kk + tx] = __float2bfloat16(tile[tx][ty + i]);
}

// ---------------- bf16 MFMA GEMM 128x128, BK=64: OUTMODE 0=f32, 1=f32+res, 2=bf16 ----------------
template <int OUTMODE>
__global__ __launch_bounds__(256) void gemm_mfma_kernel(const short* __restrict__ A,
                                                        const short* __restrict__ Bt,
                                                        const float* __restrict__ bias,
                                                        void* __restrict__ Cv,
                                                        int M, int N, int K) {
    __shared__ __align__(16) short As[128 * 64];
    __shared__ __align__(16) short Bs[128 * 64];
    int tid = threadIdx.x;
    int w = tid >> 6, lane = tid & 63;
    int quad = lane >> 4, ml = lane & 15;
    int wm = w & 1, wn = w >> 1;
    const short* Ab = A + (size_t)blockIdx.x * 128 * K;
    const short* Bb = Bt + (size_t)blockIdx.y * 128 * K;
    f32x4 acc[4][4] = {};
    int rS[4], cS[4];
#pragma unroll
    for (int i = 0; i < 4; i++) {
        int s = i * 256 + tid;
        rS[i] = s >> 3;
        cS[i] = (s & 7) ^ (rS[i] & 7);
    }
    int aoff[2][4], boff[2][4];
#pragma unroll
    for (int kc = 0; kc < 2; kc++)
#pragma unroll
        for (int t = 0; t < 4; t++) {
            int ra = wm * 64 + t * 16 + ml;
            aoff[kc][t] = ra * 64 + ((kc * 4 + quad) ^ (ra & 7)) * 8;
            int rb = wn * 64 + t * 16 + ml;
            boff[kc][t] = rb * 64 + ((kc * 4 + quad) ^ (rb & 7)) * 8;
        }
    for (int kk = 0; kk < K; kk += 64) {
#pragma unroll
        for (int i = 0; i < 4; i++) {
            gll16(Ab + (size_t)rS[i] * K + kk + cS[i] * 8, As + (size_t)(i * 256 + w * 64) * 8);
            gll16(Bb + (size_t)rS[i] * K + kk + cS[i] * 8, Bs + (size_t)(i * 256 + w * 64) * 8);
        }
        __syncthreads();
#pragma unroll
        for (int kc = 0; kc < 2; kc++) {
            short8 af[4], bfr[4];
#pragma unroll
            for (int t = 0; t < 4; t++) af[t]  = *(const short8*)&As[aoff[kc][t]];
#pragma unroll
            for (int t = 0; t < 4; t++) bfr[t] = *(const short8*)&Bs[boff[kc][t]];
#pragma unroll
            for (int mt = 0; mt < 4; mt++)
#pragma unroll
                for (int nt = 0; nt < 4; nt++)
                    acc[mt][nt] = __builtin_amdgcn_mfma_f32_16x16x32_bf16(af[mt], bfr[nt], acc[mt][nt], 0, 0, 0);
        }
        __syncthreads();
    }
#pragma unroll
    for (int mt = 0; mt < 4; mt++) {
#pragma unroll
        for (int nt = 0; nt < 4; nt++) {
            int n = blockIdx.y * 128 + wn * 64 + nt * 16 + ml;
            float bv = bias[n];
#pragma unroll
            for (int r = 0; r < 4; r++) {
                int m = blockIdx.x * 128 + wm * 64 + mt * 16 + quad * 4 + r;
                size_t off = (size_t)m * N + n;
                float v = acc[mt][nt][r] + bv;
                if (OUTMODE == 2) {
                    ((unsigned short*)Cv)[off] = __bfloat16_as_ushort(__float2bfloat16(v));
                } else {
                    float* C = (float*)Cv;
                    if (OUTMODE == 1) v += C[off];
                    C[off] = v;
                }
            }
        }
    }
}

// ---------------- bf16 MFMA GEMM 64x64, BK=64, + bias + residual (N=512 out-proj) ----------------
__global__ __launch_bounds__(256) void gemm6464_res_kernel(const short* __restrict__ A,
                                                           const short* __restrict__ Bt,
                                                           const float* __restrict__ bias,
                                                           float* __restrict__ C,
                                                           int M, int N, int K) {
    __shared__ __align__(16) short As[64 * 64];
    __shared__ __align__(16) short Bs[64 * 64];
    int tid = threadIdx.x;
    int w = tid >> 6, lane = tid & 63;
    int quad = lane >> 4, ml = lane & 15;
    int wm = w & 1, wn = w >> 1;
    const short* Ab = A + (size_t)blockIdx.x * 64 * K;
    const short* Bb = Bt + (size_t)blockIdx.y * 64 * K;
    f32x4 acc[2][2] = {};
    int rS[2], cS[2];
#pragma unroll
    for (int i = 0; i < 2; i++) {
        int s = i * 256 + tid;
        rS[i] = s >> 3;
        cS[i] = (s & 7) ^ (rS[i] & 7);
    }
    int aoff[2][2], boff[2][2];
#pragma unroll
    for (int kc = 0; kc < 2; kc++)
#pragma unroll
        for (int t = 0; t < 2; t++) {
            int ra = wm * 32 + t * 16 + ml;
            aoff[kc][t] = ra * 64 + ((kc * 4 + quad) ^ (ra & 7)) * 8;
            int rb = wn * 32 + t * 16 + ml;
            boff[kc][t] = rb * 64 + ((kc * 4 + quad) ^ (rb & 7)) * 8;
        }
    for (int kk = 0; kk < K; kk += 64) {
#pragma unroll
        for (int i = 0; i < 2; i++) {
            gll16(Ab + (size_t)rS[i] * K + kk + cS[i] * 8, As + (size_t)(i * 256 + w * 64) * 8);
            gll16(Bb + (size_t)rS[i] * K + kk + cS[i] * 8, Bs + (size_t)(i * 256 + w * 64) * 8);
        }
        __syncthreads();
#pragma unroll
        for (int kc = 0; kc < 2; kc++) {
            short8 af[2], bfr[2];
#pragma unroll
            for (int t = 0; t < 2; t++) af[t]  = *(const short8*)&As[aoff[kc][t]];
#pragma unroll
            for (int t = 0; t < 2; t++) bfr[t] = *(const short8*)&Bs[boff[kc][t]];
#pragma unroll
            for (int mt = 0; mt < 2; mt++)
#pragma unroll
                for (int nt = 0; nt < 2; nt++)
                    acc[mt][nt] = __builtin_amdgcn_mfma_f32_16x16x32_bf16(af[mt], bfr[nt], acc[mt][nt], 0, 0, 0);
        }
        __syncthreads();
    }
#pragma unroll
    for (int mt = 0; mt < 2; mt++) {
#pragma unroll
        for (int nt = 0; nt < 2; nt++) {
            int n = blockIdx.y * 64 + wn * 32 + nt * 16 + ml;
            float bv = bias[n];
#pragma unroll
            for (int r = 0; r < 4; r++) {
                int m = blockIdx.x * 64 + wm * 32 + mt * 16 + quad * 4 + r;
                size_t off = (size_t)m * N + n;
                C[off] = acc[mt][nt][r] + bv + C[off];
            }
        }
    }
}

// ---------------- causal depthwise conv (D_CONV=4) + SiLU: bf16 in/out ----------------
__global__ __launch_bounds__(256) void conv_kernel(const unsigned short* __restrict__ uzb,
                                                   const float* __restrict__ cw,
                                                   const float* __restrict__ cb,
                                                   unsigned short* __restrict__ ucb) {
    int idx = blockIdx.x * 256 + threadIdx.x;
    int e  = idx & (DI - 1);
    int bl = idx >> 10;
    int l  = bl & (SEQL - 1);
    int b  = bl >> 10;
    const unsigned short* u = uzb + (size_t)b * SEQL * 2048;
    float acc = cb[e];
#pragma unroll
    for (int k = 0; k < 4; k++) {
        int ll = l - 3 + k;
        float uv = (ll >= 0) ? bf2f(u[(size_t)ll * 2048 + e]) : 0.f;
        acc += uv * cw[e * 4 + k];
    }
    acc = acc / (1.f + __expf(-acc));
    ucb[idx] = __bfloat16_as_ushort(__float2bfloat16(acc));
}

// ---------------- skinny bf16 MFMA GEMM: dbc_part[ks][M][64] = ucb @ Wx^T ----------------
__global__ __launch_bounds__(256) void gemm64_mfma_kernel(const short* __restrict__ A,
                                                          const short* __restrict__ Bt,
                                                          float* __restrict__ part,
                                                          int M) {
    const int K = DI;
    const int Kseg = K / KS64;
    __shared__ __align__(16) short As[128 * 32];
    __shared__ __align__(16) short Bs[64 * 32];
    int tid = threadIdx.x;
    int w = tid >> 6, lane = tid & 63;
    int quad = lane >> 4, ml = lane & 15;
    int wm = w & 1, wn = w >> 1;
    int bm = blockIdx.x, ks = blockIdx.y;
    const short* Ab = A + (size_t)bm * 128 * K;
    f32x4 acc[4][2] = {};
    int s0 = tid, s1 = tid + 256;
    int r0 = s0 >> 2, c0 = (s0 & 3) ^ ((r0 >> 1) & 3);
    int r1 = s1 >> 2, c1 = (s1 & 3) ^ ((r1 >> 1) & 3);
    int rB = tid >> 2, cB = (tid & 3) ^ ((rB >> 1) & 3);
    int aoff[4], boff[2];
#pragma unroll
    for (int t = 0; t < 4; t++) {
        int ra = wm * 64 + t * 16 + ml;
        aoff[t] = ra * 32 + (quad ^ ((ra >> 1) & 3)) * 8;
    }
#pragma unroll
    for (int t = 0; t < 2; t++) {
        int rb = wn * 32 + t * 16 + ml;
        boff[t] = rb * 32 + (quad ^ ((rb >> 1) & 3)) * 8;
    }
    int k0 = ks * Kseg;
    for (int kk = k0; kk < k0 + Kseg; kk += 32) {
        gll16(Ab + (size_t)r0 * K + kk + c0 * 8, As + (size_t)(w * 64) * 8);
        gll16(Ab + (size_t)r1 * K + kk + c1 * 8, As + (size_t)(256 + w * 64) * 8);
        gll16(Bt + (size_t)rB * K + kk + cB * 8, Bs + (size_t)(w * 64) * 8);
        __syncthreads();
        short8 af[4], bfr[2];
#pragma unroll
        for (int t = 0; t < 4; t++) af[t]  = *(const short8*)&As[aoff[t]];
#pragma unroll
        for (int t = 0; t < 2; t++) bfr[t] = *(const short8*)&Bs[boff[t]];
#pragma unroll
        for (int mt = 0; mt < 4; mt++)
#pragma unroll
            for (int nt = 0; nt < 2; nt++)
                acc[mt][nt] = __builtin_amdgcn_mfma_f32_16x16x32_bf16(af[mt], bfr[nt], acc[mt][nt], 0, 0, 0);
        __syncthreads();
    }
#pragma unroll
    for (int mt = 0; mt < 4; mt++) {
#pragma unroll
        for (int nt = 0; nt < 2; nt++) {
            int n = wn * 32 + nt * 16 + ml;
#pragma unroll
            for (int r = 0; r < 4; r++) {
                int m = bm * 128 + wm * 64 + mt * 16 + quad * 4 + r;
                part[((size_t)ks * M + m) * 64 + n] = acc[mt][nt][r];
            }
        }
    }
}

// ---------------- dt (+fused repack): re-reduce partb, softplus, pack (dt|u) into
// t-transposed dub_t[b][e][t]; quarter-0 blocks emit bcb_t[b][n][t] + ssqb ----------------
__global__ __launch_bounds__(256) void dt_kernel(const float* __restrict__ part,
                                                 const float* __restrict__ Wdt,
                                                 const float* __restrict__ bdt,
                                                 const unsigned short* __restrict__ ucb,
                                                 unsigned* __restrict__ dub_t,
                                                 unsigned* __restrict__ bcb_t,
                                                 float* __restrict__ ssqb,
                                                 int M) {
    __shared__ float sdtc[32][32];
    __shared__ float swdt[32][256];
    int tid = threadIdx.x;
    int e0 = (blockIdx.x & 3) * 256;
    int m0 = (blockIdx.x >> 2) * 32;
    int mb = m0 >> 10;          // batch index (32 | 1024, so uniform per block)
    int t0 = m0 & 1023;
#pragma unroll
    for (int i = 0; i < 4; i++) {
        int idx = tid + 256 * i;
        int m = idx >> 5, r = idx & 31;
        float v = 0.f;
#pragma unroll
        for (int ks = 0; ks < KS64; ks++) v += part[((size_t)ks * M + m0 + m) * 64 + r];
        sdtc[m][r] = v;
    }
    if ((blockIdx.x & 3) == 0) {
        // fused repack: B,C cols 32..63 for these 32 m-rows -> bcb_t[b][n][t]
#pragma unroll
        for (int i = 0; i < 4; i++) {
            int idx = tid + 256 * i;
            int m = m0 + (idx >> 5);
            int j = idx & 31;
            float v = 0.f;
#pragma unroll
            for (int ks = 0; ks < KS64; ks++) v += part[((size_t)ks * M + m) * 64 + 32 + j];
            int n = j & 15;
            int tt = m & 1023;
            unsigned short u16 = __bfloat16_as_ushort(__float2bfloat16(v));
            unsigned short* bp = (unsigned short*)(bcb_t + ((size_t)mb * 16 + n) * SEQL + tt);
            if (j < 16) {
                bp[0] = u16;                       // B -> low half
            } else {
                bp[1] = u16;                       // C -> high half
                float vr = bf2f(u16);
                float s = sum16(vr * vr);
                if (j == 16) ssqb[m] = s;
            }
        }
    }
#pragma unroll
    for (int r = 0; r < 32; r++) swdt[r][tid] = Wdt[(size_t)r * DI + e0 + tid];
    __syncthreads();
    float wc[32];
#pragma unroll
    for (int r = 0; r < 32; r++) wc[r] = swdt[r][tid];
    float bv = bdt[e0 + tid];
    unsigned* dcol = dub_t + ((size_t)mb * DI + e0 + tid) * SEQL + t0;
    for (int m = 0; m < 32; m++) {
        float acc = bv;
#pragma unroll
        for (int r4 = 0; r4 < 8; r4++) {
            float4 d4 = *(const float4*)&sdtc[m][r4 * 4];
            acc = fmaf(d4.x, wc[r4 * 4 + 0], acc);
            acc = fmaf(d4.y, wc[r4 * 4 + 1], acc);
            acc = fmaf(d4.z, wc[r4 * 4 + 2], acc);
            acc = fmaf(d4.w, wc[r4 * 4 + 3], acc);
        }
        float sp = (acc > 20.f) ? acc : log1pf(__expf(acc));
        unsigned dt16 = (unsigned)__bfloat16_as_ushort(__float2bfloat16(sp));
        unsigned u16  = (unsigned)ucb[(size_t)(m0 + m) * DI + e0 + tid];
        dcol[m] = (dt16 << 16) | u16;
    }
}

// ---------------- scan v12: t-contiguous layouts, ds_read_b128 per 4 t, reg-pipelined ----------------
__device__ __forceinline__ void scan_flush(const float* yb, __hip_bfloat16* ob,
                                           int e_base, int tcp, int tid) {
#pragma unroll
    for (int r = 0; r < 2; r++) {
        int pid = r * 256 + tid;
        int t = pid >> 3, ep = pid & 7;
        float2 y2 = *(const float2*)&yb[t * YSTR + ep * 2];
        __hip_bfloat162 v;
        v.x = __float2bfloat16(y2.x);
        v.y = __float2bfloat16(y2.y);
        *(__hip_bfloat162*)&ob[(size_t)(tcp + t) * DI + e_base + ep * 2] = v;
    }
}

__global__ __launch_bounds__(256, 2) void scan_kernel(const unsigned* __restrict__ dub_t,
                                                      const unsigned short* __restrict__ uzb,
                                                      const unsigned* __restrict__ bcb_t,
                                                      const float* __restrict__ ssqb,
                                                      const float* __restrict__ Alog,
                                                      const float* __restrict__ Dv,
                                                      __hip_bfloat16* __restrict__ out) {
    __shared__ __align__(16) unsigned sDU[2][16 * SROW];
    __shared__ __align__(16) unsigned sBC[2][16 * SROW];
    __shared__ __align__(16) float    yb [2][CH * YSTR];
    int tid = threadIdx.x;
    int g = tid >> 4, n = tid & 15;
    int b = blockIdx.x >> 6;
    int e_base = (blockIdx.x & 63) << 4;
    int e = e_base + g;
    float An2 = -__expf(Alog[e * DST + n]) * 1.4426950408889634f;
    float dv = Dv[e];
    // staging mapping: row er = tid>>4 (16 rows), quad tq = (tid&15)*4 (64 t / 4)
    int er = tid >> 4, tq = (tid & 15) * 4;
    const unsigned* duRow = dub_t + ((size_t)b * DI + e_base + er) * SEQL + tq;
    const unsigned* bcRow = bcb_t + ((size_t)b * 16 + er) * SEQL + tq;
    int dst = er * SROW + tq;
    const unsigned short* zP  = uzb + (size_t)b * SEQL * 2048 + 1024 + e;
    const float*          sqP = ssqb + (size_t)b * SEQL;
    __hip_bfloat16* ob = out + (size_t)b * SEQL * DI;
    float h = 0.f;
    // prime chunk 0
    {
        uint4 a = *(const uint4*)(duRow);
        uint4 c = *(const uint4*)(bcRow);
        *(uint4*)&sDU[0][dst] = a;
        *(uint4*)&sBC[0][dst] = c;
    }
    int buf = 0;
    const int NCH = SEQL / CH;
    for (int c = 0; c < NCH; c++) {
        int tc = c * CH;
        __syncthreads();
        uint4 gdu, gbc;
        bool more = (c + 1 < NCH);
        if (more) {                       // global loads issued early; consumed at chunk end
            gdu = *(const uint4*)(duRow + tc + CH);
            gbc = *(const uint4*)(bcRow + tc + CH);
        }
        if (c > 0)
            scan_flush(yb[buf ^ 1], ob, e_base, tc - CH, tid);
        const unsigned* pDU = &sDU[buf][g * SROW];
        const unsigned* pBC = &sBC[buf][n * SROW];
        float* pY = yb[buf];
        uint4 du4 = *(const uint4*)&pDU[0];
        uint4 bc4 = *(const uint4*)&pBC[0];
        float pc = 0.f, ucap = 0.f, sq = 0.f, zv = 0.f;
#pragma unroll
        for (int p = 0; p < 16; p++) {
            uint4 duN, bcN;
            if (p < 15) {
                duN = *(const uint4*)&pDU[(p + 1) * 4];
                bcN = *(const uint4*)&pBC[(p + 1) * 4];
            }
            if ((p & 3) == 0) {           // new 16-t group: prefetch epilogue operands
                int tl = (p >> 2) * 16 + n;
                sq = sqP[tc + tl];
                zv = bf2f(zP[(size_t)(tc + tl) * 2048]);
                pc = 0.f; ucap = 0.f;
            }
            unsigned dus[4] = {du4.x, du4.y, du4.z, du4.w};
            unsigned bcs[4] = {bc4.x, bc4.y, bc4.z, bc4.w};
#pragma unroll
            for (int j = 0; j < 4; j++) {
                unsigned du = dus[j];
                float dtv = __uint_as_float(du & 0xFFFF0000u);
                float uv  = __uint_as_float(du << 16);
                unsigned bcd = bcs[j];
                float Bn = __uint_as_float(bcd << 16);
                float Cn = __uint_as_float(bcd & 0xFFFF0000u);
                float a = __builtin_amdgcn_exp2f(dtv * An2);
                h = fmaf(a, h, dtv * uv * Bn);
                float p2 = sum16(h * Cn);
                h = fmaf(uv - p2, ALPHA_C * Cn, h);
                bool cap = (n == ((p & 3) * 4 + j));
                pc   = cap ? p2 : pc;
                ucap = cap ? uv : ucap;
            }
            if ((p & 3) == 3) {           // end of 16-t group: gated output to yb
                int tl = (p >> 2) * 16 + n;
                float es2 = ALPHA_C * (ucap - pc);
                float y = fmaf(dv, ucap, fmaf(es2, sq, pc));
                float sz = zv / (1.f + __expf(-zv));
                pY[tl * YSTR + g] = y * sz;
            }
            du4 = duN; bc4 = bcN;
        }
        if (more) {                       // stage next chunk (writes to other buffer)
            *(uint4*)&sDU[buf ^ 1][dst] = gdu;
            *(uint4*)&sBC[buf ^ 1][dst] = gbc;
        }
        buf ^= 1;
    }
    __syncthreads();
    scan_flush(yb[buf ^ 1], ob, e_base, SEQL - CH, tid);
}

// ---------------- mean-pool partials ----------------
__global__ __launch_bounds__(512) void pool_kernel(const float* __restrict__ t,
                                                   float* __restrict__ part) {
    int b = blockIdx.x >> 4;
    int c = blockIdx.x & 15;
    int d = threadIdx.x;
    const float* tb = t + ((size_t)b * SEQL + c * 64) * DM + d;
    float s = 0.f;
    for (int l = 0; l < 64; l++) s += tb[(size_t)l * DM];
    part[(size_t)blockIdx.x * DM + d] = s;
}

// ---------------- final: mean, layernorm, classifier ----------------
__global__ __launch_bounds__(512) void final_kernel(const float* __restrict__ part,
                                                    const float* __restrict__ lw,
                                                    const float* __restrict__ lb,
                                                    const float* __restrict__ Wc,
                                                    const float* __restrict__ bc,
                                                    float* __restrict__ out) {
    int b = blockIdx.x;
    int d = threadIdx.x;
    float v = 0.f;
    for (int c = 0; c < 16; c++) v += part[((size_t)b * 16 + c) * DM + d];
    v *= (1.f / SEQL);
    __shared__ float sh[512], sh2[512], nd[512];
    sh[d] = v; sh2[d] = v * v;
    __syncthreads();
    for (int off = 256; off > 0; off >>= 1) {
        if (d < off) { sh[d] += sh[d + off]; sh2[d] += sh2[d + off]; }
        __syncthreads();
    }
    float mu  = sh[0]  * (1.f / DM);
    float var = sh2[0] * (1.f / DM) - mu * mu;
    float rs  = rsqrtf(var + LNEPS);
    nd[d] = (v - mu) * rs * lw[d] + lb[d];
    __syncthreads();
    if (d < 10) {
        float acc = bc[d];
        for (int k = 0; k < DM; k++) acc += nd[k] * Wc[k * 10 + d];
        out[b * 10 + d] = acc;
    }
}

extern "C" void kernel_launch(void* const* d_in, const int* in_sizes, int n_in,
                              void* d_out, int out_size, void* d_ws, size_t ws_size,
                              hipStream_t stream) {
    const float* x      = (const float*)d_in[0];
    const float* W_inp  = (const float*)d_in[1];
    const float* b_inp  = (const float*)d_in[2];
    const float* W_in   = (const float*)d_in[3];
    const float* b_in   = (const float*)d_in[4];
    const float* conv_w = (const float*)d_in[5];
    const float* conv_b = (const float*)d_in[6];
    const float* W_x    = (const float*)d_in[7];
    const float* W_dt   = (const float*)d_in[8];
    const float* b_dt   = (const float*)d_in[9];
    const float* A_log  = (const float*)d_in[10];
    const float* D_skip = (const float*)d_in[11];
    const float* W_out  = (const float*)d_in[12];
    const float* b_out  = (const float*)d_in[13];
    const float* ln_w   = (const float*)d_in[14];
    const float* ln_b   = (const float*)d_in[15];
    const float* lnf_w  = (const float*)d_in[16];
    const float* lnf_b  = (const float*)d_in[17];
    const float* W_cls  = (const float*)d_in[18];
    const float* b_cls  = (const float*)d_in[19];

    const int M = BSZ * SEQL;   // 8192

    float* ws = (float*)d_ws;
    float* t_buf = ws;                          ws += (size_t)M * DM;
    unsigned short* uzb = (unsigned short*)ws;  ws += (size_t)M * 2048 / 2;
    unsigned short* ucb = (unsigned short*)ws;  ws += (size_t)M * DI / 2;
    unsigned* dub_t = (unsigned*)ws;            ws += (size_t)M * DI;      // [b][e][t]
    unsigned* bcb_t = (unsigned*)ws;            ws += (size_t)BSZ * 16 * SEQL;  // [b][n][t]
    float* ssqb  = ws;                          ws += (size_t)M;
    unsigned short* xn_bf = (unsigned short*)ws;  ws += (size_t)M * DM / 2;
    unsigned short* ucs_bf = (unsigned short*)ws; ws += (size_t)M * DI / 2;
    float* partb = ws;                          ws += (size_t)KS64 * M * 64;
    unsigned short* wtin_bf  = (unsigned short*)ws; ws += (size_t)NLAYERS * DM * 2048 / 2;
    unsigned short* wtout_bf = (unsigned short*)ws; ws += (size_t)NLAYERS * DI * DM / 2;
    unsigned short* wxt_bf   = (unsigned short*)ws; ws += (size_t)NLAYERS * DI * 64 / 2 + 64;
    float* poolp = ws;                          ws += (size_t)128 * DM;

    embed_kernel<<<(M * DM + 255) / 256, 256, 0, stream>>>(x, W_inp, b_inp, t_buf);
    transpose_bf_kernel<<<dim3(DM / 32, 2048 / 32, NLAYERS), 256, 0, stream>>>(
        W_in, (__hip_bfloat16*)wtin_bf, DM, 2048, (size_t)DM * 2048);
    transpose_bf_kernel<<<dim3(DI / 32, DM / 32, NLAYERS), 256, 0, stream>>>(
        W_out, (__hip_bfloat16*)wtout_bf, DI, DM, (size_t)DI * DM);
    transpose_bf_kernel<<<dim3(DI / 32, 64 / 32, NLAYERS), 256, 0, stream>>>(
        W_x, (__hip_bfloat16*)wxt_bf, DI, 64, (size_t)DI * 64);

    for (int i = 0; i < NLAYERS; i++) {
        ln_kernel<<<M, 256, 0, stream>>>(t_buf, ln_w + i * DM, ln_b + i * DM,
                                         (__hip_bfloat16*)xn_bf);
        gemm_mfma_kernel<2><<<dim3(M / 128, 2048 / 128), 256, 0, stream>>>(
            (const short*)xn_bf, (const short*)(wtin_bf + (size_t)i * DM * 2048),
            b_in + i * 2048, uzb, M, 2048, DM);
        conv_kernel<<<(M * DI) / 256, 256, 0, stream>>>(
            uzb, conv_w + (size_t)i * DI * 4, conv_b + i * DI, ucb);
        gemm64_mfma_kernel<<<dim3(M / 128, KS64), 256, 0, stream>>>(
            (const short*)ucb, (const short*)(wxt_bf + (size_t)i * DI * 64), partb, M);
        dt_kernel<<<(M / 32) * 4, 256, 0, stream>>>(
            partb, W_dt + (size_t)i * DTR * DI, b_dt + i * DI, ucb, dub_t, bcb_t, ssqb, M);
        scan_kernel<<<BSZ * DI / 16, 256, 0, stream>>>(
            dub_t, uzb, bcb_t, ssqb, A_log + (size_t)i * DI * DST, D_skip + i * DI,
            (__hip_bfloat16*)ucs_bf);
        gemm6464_res_kernel<<<dim3(M / 64, DM / 64), 256, 0, stream>>>(
            (const short*)ucs_bf, (const short*)(wtout_bf + (size_t)i * DI * DM),
            b_out + i * DM, t_buf, M, DM, DI);
    }

    pool_kernel<<<128, 512, 0, stream>>>(t_buf, poolp);
    final_kernel<<<8, 512, 0, stream>>>(poolp, lnf_w, lnf_b, W_cls, b_cls, (float*)d_out);
}

// Round 13
// 1082.868 us; speedup vs baseline: 1.2812x; 1.2812x over previous
//
#include <hip/hip_runtime.h>
#include <hip/hip_bf16.h>
#include <math.h>

#define BSZ 8
#define SEQL 1024
#define DM 512
#define DI 1024
#define DST 16
#define DTR 32
#define NLAYERS 4
#define ALPHA_C 0.2f
#define LNEPS 1e-5f
#define CH 64          // scan LDS chunk length (t-steps)
#define KS64 8         // split-K for the skinny N=64 MFMA GEMM
#define YSTR 18        // yb row stride (dwords)
#define SROW 68        // scan staging row stride (dwords): 272B = 17*16B

typedef __attribute__((ext_vector_type(8))) short short8;
typedef __attribute__((ext_vector_type(4))) float f32x4;

__device__ __forceinline__ void gll16(const void* g, void* l) {
    __builtin_amdgcn_global_load_lds(
        (const __attribute__((address_space(1))) unsigned int*)g,
        (__attribute__((address_space(3))) unsigned int*)l, 16, 0, 0);
}

__device__ __forceinline__ float sum16(float x) {
    x += __int_as_float(__builtin_amdgcn_update_dpp(0, __float_as_int(x), 0x121, 0xf, 0xf, true));
    x += __int_as_float(__builtin_amdgcn_update_dpp(0, __float_as_int(x), 0x122, 0xf, 0xf, true));
    x += __int_as_float(__builtin_amdgcn_update_dpp(0, __float_as_int(x), 0x124, 0xf, 0xf, true));
    x += __int_as_float(__builtin_amdgcn_update_dpp(0, __float_as_int(x), 0x128, 0xf, 0xf, true));
    return x;
}

__device__ __forceinline__ float bf2f(unsigned short v) {
    return __uint_as_float(((unsigned)v) << 16);
}

// ---------------- input embedding ----------------
__global__ __launch_bounds__(256) void embed_kernel(const float* __restrict__ x,
                                                    const float* __restrict__ Wi,
                                                    const float* __restrict__ bi,
                                                    float* __restrict__ t) {
    int idx = blockIdx.x * 256 + threadIdx.x;
    if (idx >= BSZ * SEQL * DM) return;
    int d  = idx & (DM - 1);
    int bl = idx >> 9;
    int l  = bl & (SEQL - 1);
    int b  = bl >> 10;
    const float* xb = x + (size_t)b * 3 * SEQL;
    float acc = bi[d];
    acc += xb[0 * SEQL + l] * Wi[0 * DM + d];
    acc += xb[1 * SEQL + l] * Wi[1 * DM + d];
    acc += xb[2 * SEQL + l] * Wi[2 * DM + d];
    t[idx] = acc;
}

// ---------------- layernorm over DM=512, writes bf16 ----------------
__global__ __launch_bounds__(256) void ln_kernel(const float* __restrict__ t,
                                                 const float* __restrict__ w,
                                                 const float* __restrict__ b,
                                                 __hip_bfloat16* __restrict__ xn) {
    int row = blockIdx.x;
    int tid = threadIdx.x;
    const float* r = t + (size_t)row * DM;
    float v0 = r[tid], v1 = r[tid + 256];
    __shared__ float sh[256], sh2[256];
    sh[tid]  = v0 + v1;
    sh2[tid] = v0 * v0 + v1 * v1;
    __syncthreads();
    for (int off = 128; off > 0; off >>= 1) {
        if (tid < off) { sh[tid] += sh[tid + off]; sh2[tid] += sh2[tid + off]; }
        __syncthreads();
    }
    float mu  = sh[0]  * (1.f / DM);
    float var = sh2[0] * (1.f / DM) - mu * mu;
    float rs  = rsqrtf(var + LNEPS);
    xn[(size_t)row * DM + tid]       = __float2bfloat16((v0 - mu) * rs * w[tid]       + b[tid]);
    xn[(size_t)row * DM + tid + 256] = __float2bfloat16((v1 - mu) * rs * w[tid + 256] + b[tid + 256]);
}

// ---------------- transpose + fp32->bf16: W[K][N] -> Wt[N][K] ----------------
__global__ __launch_bounds__(256) void transpose_bf_kernel(const float* __restrict__ W,
                                                           __hip_bfloat16* __restrict__ Wt,
                                                           int K, int N, size_t lstride) {
    const float* Wl = W + (size_t)blockIdx.z * lstride;
    __hip_bfloat16* Wtl = Wt + (size_t)blockIdx.z * lstride;
    __shared__ float tile[32][33];
    int kk = blockIdx.x * 32, nn = blockIdx.y * 32;
    int tx = threadIdx.x & 31, ty = threadIdx.x >> 5;
#pragma unroll
    for (int i = 0; i < 32; i += 8)
        tile[ty + i][tx] = Wl[(size_t)(kk + ty + i) * N + nn + tx];
    __syncthreads();
#pragma unroll
    for (int i = 0; i < 32; i += 8)
        Wtl[(size_t)(nn + ty + i) * K + kk + tx] = __float2bfloat16(tile[tx][ty + i]);
}

// ---------------- bf16 MFMA GEMM 128x128, BK=64: OUTMODE 0=f32, 1=f32+res, 2=bf16 ----------------
template <int OUTMODE>
__global__ __launch_bounds__(256) void gemm_mfma_kernel(const short* __restrict__ A,
                                                        const short* __restrict__ Bt,
                                                        const float* __restrict__ bias,
                                                        void* __restrict__ Cv,
                                                        int M, int N, int K) {
    __shared__ __align__(16) short As[128 * 64];
    __shared__ __align__(16) short Bs[128 * 64];
    int tid = threadIdx.x;
    int w = tid >> 6, lane = tid & 63;
    int quad = lane >> 4, ml = lane & 15;
    int wm = w & 1, wn = w >> 1;
    const short* Ab = A + (size_t)blockIdx.x * 128 * K;
    const short* Bb = Bt + (size_t)blockIdx.y * 128 * K;
    f32x4 acc[4][4] = {};
    int rS[4], cS[4];
#pragma unroll
    for (int i = 0; i < 4; i++) {
        int s = i * 256 + tid;
        rS[i] = s >> 3;
        cS[i] = (s & 7) ^ (rS[i] & 7);
    }
    int aoff[2][4], boff[2][4];
#pragma unroll
    for (int kc = 0; kc < 2; kc++)
#pragma unroll
        for (int t = 0; t < 4; t++) {
            int ra = wm * 64 + t * 16 + ml;
            aoff[kc][t] = ra * 64 + ((kc * 4 + quad) ^ (ra & 7)) * 8;
            int rb = wn * 64 + t * 16 + ml;
            boff[kc][t] = rb * 64 + ((kc * 4 + quad) ^ (rb & 7)) * 8;
        }
    for (int kk = 0; kk < K; kk += 64) {
#pragma unroll
        for (int i = 0; i < 4; i++) {
            gll16(Ab + (size_t)rS[i] * K + kk + cS[i] * 8, As + (size_t)(i * 256 + w * 64) * 8);
            gll16(Bb + (size_t)rS[i] * K + kk + cS[i] * 8, Bs + (size_t)(i * 256 + w * 64) * 8);
        }
        __syncthreads();
#pragma unroll
        for (int kc = 0; kc < 2; kc++) {
            short8 af[4], bfr[4];
#pragma unroll
            for (int t = 0; t < 4; t++) af[t]  = *(const short8*)&As[aoff[kc][t]];
#pragma unroll
            for (int t = 0; t < 4; t++) bfr[t] = *(const short8*)&Bs[boff[kc][t]];
#pragma unroll
            for (int mt = 0; mt < 4; mt++)
#pragma unroll
                for (int nt = 0; nt < 4; nt++)
                    acc[mt][nt] = __builtin_amdgcn_mfma_f32_16x16x32_bf16(af[mt], bfr[nt], acc[mt][nt], 0, 0, 0);
        }
        __syncthreads();
    }
#pragma unroll
    for (int mt = 0; mt < 4; mt++) {
#pragma unroll
        for (int nt = 0; nt < 4; nt++) {
            int n = blockIdx.y * 128 + wn * 64 + nt * 16 + ml;
            float bv = bias[n];
#pragma unroll
            for (int r = 0; r < 4; r++) {
                int m = blockIdx.x * 128 + wm * 64 + mt * 16 + quad * 4 + r;
                size_t off = (size_t)m * N + n;
                float v = acc[mt][nt][r] + bv;
                if (OUTMODE == 2) {
                    ((unsigned short*)Cv)[off] = __bfloat16_as_ushort(__float2bfloat16(v));
                } else {
                    float* C = (float*)Cv;
                    if (OUTMODE == 1) v += C[off];
                    C[off] = v;
                }
            }
        }
    }
}

// ---------------- bf16 MFMA GEMM 64x64, BK=64, + bias + residual (N=512 out-proj) ----------------
__global__ __launch_bounds__(256) void gemm6464_res_kernel(const short* __restrict__ A,
                                                           const short* __restrict__ Bt,
                                                           const float* __restrict__ bias,
                                                           float* __restrict__ C,
                                                           int M, int N, int K) {
    __shared__ __align__(16) short As[64 * 64];
    __shared__ __align__(16) short Bs[64 * 64];
    int tid = threadIdx.x;
    int w = tid >> 6, lane = tid & 63;
    int quad = lane >> 4, ml = lane & 15;
    int wm = w & 1, wn = w >> 1;
    const short* Ab = A + (size_t)blockIdx.x * 64 * K;
    const short* Bb = Bt + (size_t)blockIdx.y * 64 * K;
    f32x4 acc[2][2] = {};
    int rS[2], cS[2];
#pragma unroll
    for (int i = 0; i < 2; i++) {
        int s = i * 256 + tid;
        rS[i] = s >> 3;
        cS[i] = (s & 7) ^ (rS[i] & 7);
    }
    int aoff[2][2], boff[2][2];
#pragma unroll
    for (int kc = 0; kc < 2; kc++)
#pragma unroll
        for (int t = 0; t < 2; t++) {
            int ra = wm * 32 + t * 16 + ml;
            aoff[kc][t] = ra * 64 + ((kc * 4 + quad) ^ (ra & 7)) * 8;
            int rb = wn * 32 + t * 16 + ml;
            boff[kc][t] = rb * 64 + ((kc * 4 + quad) ^ (rb & 7)) * 8;
        }
    for (int kk = 0; kk < K; kk += 64) {
#pragma unroll
        for (int i = 0; i < 2; i++) {
            gll16(Ab + (size_t)rS[i] * K + kk + cS[i] * 8, As + (size_t)(i * 256 + w * 64) * 8);
            gll16(Bb + (size_t)rS[i] * K + kk + cS[i] * 8, Bs + (size_t)(i * 256 + w * 64) * 8);
        }
        __syncthreads();
#pragma unroll
        for (int kc = 0; kc < 2; kc++) {
            short8 af[2], bfr[2];
#pragma unroll
            for (int t = 0; t < 2; t++) af[t]  = *(const short8*)&As[aoff[kc][t]];
#pragma unroll
            for (int t = 0; t < 2; t++) bfr[t] = *(const short8*)&Bs[boff[kc][t]];
#pragma unroll
            for (int mt = 0; mt < 2; mt++)
#pragma unroll
                for (int nt = 0; nt < 2; nt++)
                    acc[mt][nt] = __builtin_amdgcn_mfma_f32_16x16x32_bf16(af[mt], bfr[nt], acc[mt][nt], 0, 0, 0);
        }
        __syncthreads();
    }
#pragma unroll
    for (int mt = 0; mt < 2; mt++) {
#pragma unroll
        for (int nt = 0; nt < 2; nt++) {
            int n = blockIdx.y * 64 + wn * 32 + nt * 16 + ml;
            float bv = bias[n];
#pragma unroll
            for (int r = 0; r < 4; r++) {
                int m = blockIdx.x * 64 + wm * 32 + mt * 16 + quad * 4 + r;
                size_t off = (size_t)m * N + n;
                C[off] = acc[mt][nt][r] + bv + C[off];
            }
        }
    }
}

// ---------------- causal depthwise conv (D_CONV=4) + SiLU: bf16 in/out ----------------
__global__ __launch_bounds__(256) void conv_kernel(const unsigned short* __restrict__ uzb,
                                                   const float* __restrict__ cw,
                                                   const float* __restrict__ cb,
                                                   unsigned short* __restrict__ ucb) {
    int idx = blockIdx.x * 256 + threadIdx.x;
    int e  = idx & (DI - 1);
    int bl = idx >> 10;
    int l  = bl & (SEQL - 1);
    int b  = bl >> 10;
    const unsigned short* u = uzb + (size_t)b * SEQL * 2048;
    float acc = cb[e];
#pragma unroll
    for (int k = 0; k < 4; k++) {
        int ll = l - 3 + k;
        float uv = (ll >= 0) ? bf2f(u[(size_t)ll * 2048 + e]) : 0.f;
        acc += uv * cw[e * 4 + k];
    }
    acc = acc / (1.f + __expf(-acc));
    ucb[idx] = __bfloat16_as_ushort(__float2bfloat16(acc));
}

// ---------------- skinny bf16 MFMA GEMM: dbc_part[ks][M][64] = ucb @ Wx^T ----------------
__global__ __launch_bounds__(256) void gemm64_mfma_kernel(const short* __restrict__ A,
                                                          const short* __restrict__ Bt,
                                                          float* __restrict__ part,
                                                          int M) {
    const int K = DI;
    const int Kseg = K / KS64;
    __shared__ __align__(16) short As[128 * 32];
    __shared__ __align__(16) short Bs[64 * 32];
    int tid = threadIdx.x;
    int w = tid >> 6, lane = tid & 63;
    int quad = lane >> 4, ml = lane & 15;
    int wm = w & 1, wn = w >> 1;
    int bm = blockIdx.x, ks = blockIdx.y;
    const short* Ab = A + (size_t)bm * 128 * K;
    f32x4 acc[4][2] = {};
    int s0 = tid, s1 = tid + 256;
    int r0 = s0 >> 2, c0 = (s0 & 3) ^ ((r0 >> 1) & 3);
    int r1 = s1 >> 2, c1 = (s1 & 3) ^ ((r1 >> 1) & 3);
    int rB = tid >> 2, cB = (tid & 3) ^ ((rB >> 1) & 3);
    int aoff[4], boff[2];
#pragma unroll
    for (int t = 0; t < 4; t++) {
        int ra = wm * 64 + t * 16 + ml;
        aoff[t] = ra * 32 + (quad ^ ((ra >> 1) & 3)) * 8;
    }
#pragma unroll
    for (int t = 0; t < 2; t++) {
        int rb = wn * 32 + t * 16 + ml;
        boff[t] = rb * 32 + (quad ^ ((rb >> 1) & 3)) * 8;
    }
    int k0 = ks * Kseg;
    for (int kk = k0; kk < k0 + Kseg; kk += 32) {
        gll16(Ab + (size_t)r0 * K + kk + c0 * 8, As + (size_t)(w * 64) * 8);
        gll16(Ab + (size_t)r1 * K + kk + c1 * 8, As + (size_t)(256 + w * 64) * 8);
        gll16(Bt + (size_t)rB * K + kk + cB * 8, Bs + (size_t)(w * 64) * 8);
        __syncthreads();
        short8 af[4], bfr[2];
#pragma unroll
        for (int t = 0; t < 4; t++) af[t]  = *(const short8*)&As[aoff[t]];
#pragma unroll
        for (int t = 0; t < 2; t++) bfr[t] = *(const short8*)&Bs[boff[t]];
#pragma unroll
        for (int mt = 0; mt < 4; mt++)
#pragma unroll
            for (int nt = 0; nt < 2; nt++)
                acc[mt][nt] = __builtin_amdgcn_mfma_f32_16x16x32_bf16(af[mt], bfr[nt], acc[mt][nt], 0, 0, 0);
        __syncthreads();
    }
#pragma unroll
    for (int mt = 0; mt < 4; mt++) {
#pragma unroll
        for (int nt = 0; nt < 2; nt++) {
            int n = wn * 32 + nt * 16 + ml;
#pragma unroll
            for (int r = 0; r < 4; r++) {
                int m = bm * 128 + wm * 64 + mt * 16 + quad * 4 + r;
                part[((size_t)ks * M + m) * 64 + n] = acc[mt][nt][r];
            }
        }
    }
}

// ---------------- dt (+fused repack): reduce partb, softplus, pack (dt|u);
// LDS-transposed burst write to dub_t[b][e][t]; quarter-0 also emits bcb_t + ssqb ----------------
__global__ __launch_bounds__(256) void dt_kernel(const float* __restrict__ part,
                                                 const float* __restrict__ Wdt,
                                                 const float* __restrict__ bdt,
                                                 const unsigned short* __restrict__ ucb,
                                                 unsigned* __restrict__ dub_t,
                                                 unsigned* __restrict__ bcb_t,
                                                 float* __restrict__ ssqb,
                                                 int M) {
    __shared__ float sdtc[32][32];
    __shared__ unsigned dtile[256 * 33];   // [e_local][t] pad 33: writes 2-way (free)
    int tid = threadIdx.x;
    int e0 = (blockIdx.x & 3) * 256;
    int m0 = (blockIdx.x >> 2) * 32;
    int mb = m0 >> 10;          // batch index
    int t0 = m0 & 1023;
#pragma unroll
    for (int i = 0; i < 4; i++) {
        int idx = tid + 256 * i;
        int m = idx >> 5, r = idx & 31;
        float v = 0.f;
#pragma unroll
        for (int ks = 0; ks < KS64; ks++) v += part[((size_t)ks * M + m0 + m) * 64 + r];
        sdtc[m][r] = v;
    }
    if ((blockIdx.x & 3) == 0) {
        // fused repack: B,C cols 32..63 for these 32 m-rows -> bcb_t[b][n][t]
#pragma unroll
        for (int i = 0; i < 4; i++) {
            int idx = tid + 256 * i;
            int m = m0 + (idx >> 5);
            int j = idx & 31;
            float v = 0.f;
#pragma unroll
            for (int ks = 0; ks < KS64; ks++) v += part[((size_t)ks * M + m) * 64 + 32 + j];
            int n = j & 15;
            int tt = m & 1023;
            unsigned short u16 = __bfloat16_as_ushort(__float2bfloat16(v));
            unsigned short* bp = (unsigned short*)(bcb_t + ((size_t)mb * 16 + n) * SEQL + tt);
            if (j < 16) {
                bp[0] = u16;                       // B -> low half
            } else {
                bp[1] = u16;                       // C -> high half
                float vr = bf2f(u16);
                float s = sum16(vr * vr);
                if (j == 16) ssqb[m] = s;
            }
        }
    }
    // Wdt column direct to registers (coalesced; L2-resident, shared across blocks)
    float wc[32];
#pragma unroll
    for (int r = 0; r < 32; r++) wc[r] = Wdt[(size_t)r * DI + e0 + tid];
    float bv = bdt[e0 + tid];
    __syncthreads();
    for (int m = 0; m < 32; m++) {
        float acc = bv;
#pragma unroll
        for (int r4 = 0; r4 < 8; r4++) {
            float4 d4 = *(const float4*)&sdtc[m][r4 * 4];
            acc = fmaf(d4.x, wc[r4 * 4 + 0], acc);
            acc = fmaf(d4.y, wc[r4 * 4 + 1], acc);
            acc = fmaf(d4.z, wc[r4 * 4 + 2], acc);
            acc = fmaf(d4.w, wc[r4 * 4 + 3], acc);
        }
        float sp = (acc > 20.f) ? acc : log1pf(__expf(acc));
        unsigned dt16 = (unsigned)__bfloat16_as_ushort(__float2bfloat16(sp));
        unsigned u16  = (unsigned)ucb[(size_t)(m0 + m) * DI + e0 + tid];
        dtile[tid * 33 + m] = (dt16 << 16) | u16;
    }
    __syncthreads();
    // burst transposed write-out: 8 lanes per e-row -> one 128B contiguous segment each
    unsigned* dwr = dub_t + ((size_t)mb * DI + e0) * SEQL + t0;
#pragma unroll
    for (int it = 0; it < 8; it++) {
        int idx = it * 256 + tid;
        int el = idx >> 3;
        int c  = (idx & 7) * 4;
        uint4 v;
        v.x = dtile[el * 33 + c + 0];
        v.y = dtile[el * 33 + c + 1];
        v.z = dtile[el * 33 + c + 2];
        v.w = dtile[el * 33 + c + 3];
        *(uint4*)(dwr + (size_t)el * SEQL + c) = v;
    }
}

// ---------------- scan v12 (kept): t-contiguous layouts, ds_read_b128 per 4 t ----------------
__device__ __forceinline__ void scan_flush(const float* yb, __hip_bfloat16* ob,
                                           int e_base, int tcp, int tid) {
#pragma unroll
    for (int r = 0; r < 2; r++) {
        int pid = r * 256 + tid;
        int t = pid >> 3, ep = pid & 7;
        float2 y2 = *(const float2*)&yb[t * YSTR + ep * 2];
        __hip_bfloat162 v;
        v.x = __float2bfloat16(y2.x);
        v.y = __float2bfloat16(y2.y);
        *(__hip_bfloat162*)&ob[(size_t)(tcp + t) * DI + e_base + ep * 2] = v;
    }
}

__global__ __launch_bounds__(256, 2) void scan_kernel(const unsigned* __restrict__ dub_t,
                                                      const unsigned short* __restrict__ uzb,
                                                      const unsigned* __restrict__ bcb_t,
                                                      const float* __restrict__ ssqb,
                                                      const float* __restrict__ Alog,
                                                      const float* __restrict__ Dv,
                                                      __hip_bfloat16* __restrict__ out) {
    __shared__ __align__(16) unsigned sDU[2][16 * SROW];
    __shared__ __align__(16) unsigned sBC[2][16 * SROW];
    __shared__ __align__(16) float    yb [2][CH * YSTR];
    int tid = threadIdx.x;
    int g = tid >> 4, n = tid & 15;
    int b = blockIdx.x >> 6;
    int e_base = (blockIdx.x & 63) << 4;
    int e = e_base + g;
    float An2 = -__expf(Alog[e * DST + n]) * 1.4426950408889634f;
    float dv = Dv[e];
    int er = tid >> 4, tq = (tid & 15) * 4;
    const unsigned* duRow = dub_t + ((size_t)b * DI + e_base + er) * SEQL + tq;
    const unsigned* bcRow = bcb_t + ((size_t)b * 16 + er) * SEQL + tq;
    int dst = er * SROW + tq;
    const unsigned short* zP  = uzb + (size_t)b * SEQL * 2048 + 1024 + e;
    const float*          sqP = ssqb + (size_t)b * SEQL;
    __hip_bfloat16* ob = out + (size_t)b * SEQL * DI;
    float h = 0.f;
    {
        uint4 a = *(const uint4*)(duRow);
        uint4 c = *(const uint4*)(bcRow);
        *(uint4*)&sDU[0][dst] = a;
        *(uint4*)&sBC[0][dst] = c;
    }
    int buf = 0;
    const int NCH = SEQL / CH;
    for (int c = 0; c < NCH; c++) {
        int tc = c * CH;
        __syncthreads();
        uint4 gdu, gbc;
        bool more = (c + 1 < NCH);
        if (more) {
            gdu = *(const uint4*)(duRow + tc + CH);
            gbc = *(const uint4*)(bcRow + tc + CH);
        }
        if (c > 0)
            scan_flush(yb[buf ^ 1], ob, e_base, tc - CH, tid);
        const unsigned* pDU = &sDU[buf][g * SROW];
        const unsigned* pBC = &sBC[buf][n * SROW];
        float* pY = yb[buf];
        uint4 du4 = *(const uint4*)&pDU[0];
        uint4 bc4 = *(const uint4*)&pBC[0];
        float pc = 0.f, ucap = 0.f, sq = 0.f, zv = 0.f;
#pragma unroll
        for (int p = 0; p < 16; p++) {
            uint4 duN, bcN;
            if (p < 15) {
                duN = *(const uint4*)&pDU[(p + 1) * 4];
                bcN = *(const uint4*)&pBC[(p + 1) * 4];
            }
            if ((p & 3) == 0) {
                int tl = (p >> 2) * 16 + n;
                sq = sqP[tc + tl];
                zv = bf2f(zP[(size_t)(tc + tl) * 2048]);
                pc = 0.f; ucap = 0.f;
            }
            unsigned dus[4] = {du4.x, du4.y, du4.z, du4.w};
            unsigned bcs[4] = {bc4.x, bc4.y, bc4.z, bc4.w};
#pragma unroll
            for (int j = 0; j < 4; j++) {
                unsigned du = dus[j];
                float dtv = __uint_as_float(du & 0xFFFF0000u);
                float uv  = __uint_as_float(du << 16);
                unsigned bcd = bcs[j];
                float Bn = __uint_as_float(bcd << 16);
                float Cn = __uint_as_float(bcd & 0xFFFF0000u);
                float a = __builtin_amdgcn_exp2f(dtv * An2);
                h = fmaf(a, h, dtv * uv * Bn);
                float p2 = sum16(h * Cn);
                h = fmaf(uv - p2, ALPHA_C * Cn, h);
                bool cap = (n == ((p & 3) * 4 + j));
                pc   = cap ? p2 : pc;
                ucap = cap ? uv : ucap;
            }
            if ((p & 3) == 3) {
                int tl = (p >> 2) * 16 + n;
                float es2 = ALPHA_C * (ucap - pc);
                float y = fmaf(dv, ucap, fmaf(es2, sq, pc));
                float sz = zv / (1.f + __expf(-zv));
                pY[tl * YSTR + g] = y * sz;
            }
            du4 = duN; bc4 = bcN;
        }
        if (more) {
            *(uint4*)&sDU[buf ^ 1][dst] = gdu;
            *(uint4*)&sBC[buf ^ 1][dst] = gbc;
        }
        buf ^= 1;
    }
    __syncthreads();
    scan_flush(yb[buf ^ 1], ob, e_base, SEQL - CH, tid);
}

// ---------------- mean-pool partials ----------------
__global__ __launch_bounds__(512) void pool_kernel(const float* __restrict__ t,
                                                   float* __restrict__ part) {
    int b = blockIdx.x >> 4;
    int c = blockIdx.x & 15;
    int d = threadIdx.x;
    const float* tb = t + ((size_t)b * SEQL + c * 64) * DM + d;
    float s = 0.f;
    for (int l = 0; l < 64; l++) s += tb[(size_t)l * DM];
    part[(size_t)blockIdx.x * DM + d] = s;
}

// ---------------- final: mean, layernorm, classifier ----------------
__global__ __launch_bounds__(512) void final_kernel(const float* __restrict__ part,
                                                    const float* __restrict__ lw,
                                                    const float* __restrict__ lb,
                                                    const float* __restrict__ Wc,
                                                    const float* __restrict__ bc,
                                                    float* __restrict__ out) {
    int b = blockIdx.x;
    int d = threadIdx.x;
    float v = 0.f;
    for (int c = 0; c < 16; c++) v += part[((size_t)b * 16 + c) * DM + d];
    v *= (1.f / SEQL);
    __shared__ float sh[512], sh2[512], nd[512];
    sh[d] = v; sh2[d] = v * v;
    __syncthreads();
    for (int off = 256; off > 0; off >>= 1) {
        if (d < off) { sh[d] += sh[d + off]; sh2[d] += sh2[d + off]; }
        __syncthreads();
    }
    float mu  = sh[0]  * (1.f / DM);
    float var = sh2[0] * (1.f / DM) - mu * mu;
    float rs  = rsqrtf(var + LNEPS);
    nd[d] = (v - mu) * rs * lw[d] + lb[d];
    __syncthreads();
    if (d < 10) {
        float acc = bc[d];
        for (int k = 0; k < DM; k++) acc += nd[k] * Wc[k * 10 + d];
        out[b * 10 + d] = acc;
    }
}

extern "C" void kernel_launch(void* const* d_in, const int* in_sizes, int n_in,
                              void* d_out, int out_size, void* d_ws, size_t ws_size,
                              hipStream_t stream) {
    const float* x      = (const float*)d_in[0];
    const float* W_inp  = (const float*)d_in[1];
    const float* b_inp  = (const float*)d_in[2];
    const float* W_in   = (const float*)d_in[3];
    const float* b_in   = (const float*)d_in[4];
    const float* conv_w = (const float*)d_in[5];
    const float* conv_b = (const float*)d_in[6];
    const float* W_x    = (const float*)d_in[7];
    const float* W_dt   = (const float*)d_in[8];
    const float* b_dt   = (const float*)d_in[9];
    const float* A_log  = (const float*)d_in[10];
    const float* D_skip = (const float*)d_in[11];
    const float* W_out  = (const float*)d_in[12];
    const float* b_out  = (const float*)d_in[13];
    const float* ln_w   = (const float*)d_in[14];
    const float* ln_b   = (const float*)d_in[15];
    const float* lnf_w  = (const float*)d_in[16];
    const float* lnf_b  = (const float*)d_in[17];
    const float* W_cls  = (const float*)d_in[18];
    const float* b_cls  = (const float*)d_in[19];

    const int M = BSZ * SEQL;   // 8192

    float* ws = (float*)d_ws;
    float* t_buf = ws;                          ws += (size_t)M * DM;
    unsigned short* uzb = (unsigned short*)ws;  ws += (size_t)M * 2048 / 2;
    unsigned short* ucb = (unsigned short*)ws;  ws += (size_t)M * DI / 2;
    unsigned* dub_t = (unsigned*)ws;            ws += (size_t)M * DI;      // [b][e][t]
    unsigned* bcb_t = (unsigned*)ws;            ws += (size_t)BSZ * 16 * SEQL;  // [b][n][t]
    float* ssqb  = ws;                          ws += (size_t)M;
    unsigned short* xn_bf = (unsigned short*)ws;  ws += (size_t)M * DM / 2;
    unsigned short* ucs_bf = (unsigned short*)ws; ws += (size_t)M * DI / 2;
    float* partb = ws;                          ws += (size_t)KS64 * M * 64;
    unsigned short* wtin_bf  = (unsigned short*)ws; ws += (size_t)NLAYERS * DM * 2048 / 2;
    unsigned short* wtout_bf = (unsigned short*)ws; ws += (size_t)NLAYERS * DI * DM / 2;
    unsigned short* wxt_bf   = (unsigned short*)ws; ws += (size_t)NLAYERS * DI * 64 / 2 + 64;
    float* poolp = ws;                          ws += (size_t)128 * DM;

    embed_kernel<<<(M * DM + 255) / 256, 256, 0, stream>>>(x, W_inp, b_inp, t_buf);
    transpose_bf_kernel<<<dim3(DM / 32, 2048 / 32, NLAYERS), 256, 0, stream>>>(
        W_in, (__hip_bfloat16*)wtin_bf, DM, 2048, (size_t)DM * 2048);
    transpose_bf_kernel<<<dim3(DI / 32, DM / 32, NLAYERS), 256, 0, stream>>>(
        W_out, (__hip_bfloat16*)wtout_bf, DI, DM, (size_t)DI * DM);
    transpose_bf_kernel<<<dim3(DI / 32, 64 / 32, NLAYERS), 256, 0, stream>>>(
        W_x, (__hip_bfloat16*)wxt_bf, DI, 64, (size_t)DI * 64);

    for (int i = 0; i < NLAYERS; i++) {
        ln_kernel<<<M, 256, 0, stream>>>(t_buf, ln_w + i * DM, ln_b + i * DM,
                                         (__hip_bfloat16*)xn_bf);
        gemm_mfma_kernel<2><<<dim3(M / 128, 2048 / 128), 256, 0, stream>>>(
            (const short*)xn_bf, (const short*)(wtin_bf + (size_t)i * DM * 2048),
            b_in + i * 2048, uzb, M, 2048, DM);
        conv_kernel<<<(M * DI) / 256, 256, 0, stream>>>(
            uzb, conv_w + (size_t)i * DI * 4, conv_b + i * DI, ucb);
        gemm64_mfma_kernel<<<dim3(M / 128, KS64), 256, 0, stream>>>(
            (const short*)ucb, (const short*)(wxt_bf + (size_t)i * DI * 64), partb, M);
        dt_kernel<<<(M / 32) * 4, 256, 0, stream>>>(
            partb, W_dt + (size_t)i * DTR * DI, b_dt + i * DI, ucb, dub_t, bcb_t, ssqb, M);
        scan_kernel<<<BSZ * DI / 16, 256, 0, stream>>>(
            dub_t, uzb, bcb_t, ssqb, A_log + (size_t)i * DI * DST, D_skip + i * DI,
            (__hip_bfloat16*)ucs_bf);
        gemm6464_res_kernel<<<dim3(M / 64, DM / 64), 256, 0, stream>>>(
            (const short*)ucs_bf, (const short*)(wtout_bf + (size_t)i * DI * DM),
            b_out + i * DM, t_buf, M, DM, DI);
    }

    pool_kernel<<<128, 512, 0, stream>>>(t_buf, poolp);
    final_kernel<<<8, 512, 0, stream>>>(poolp, lnf_w, lnf_b, W_cls, b_cls, (float*)d_out);
}